// Round 2
// baseline (11923.729 us; speedup 1.0000x reference)
//
#include <hip/hip_runtime.h>
#include <math.h>

#define CB 64
#define CT 512
#define CD 256
#define CH 1024
#define CV 32000

// ---- LDS layouts ----
// RNN h-tile / U-slice: row stride 1152 floats; each 32-float K-chunk padded
// to 36 floats; within-chunk float4 slot XOR-swizzled by ((row>>2)&3)<<3.
// XOR swizzle is bijective (round-1 bug: additive swizzle collided, clobbering
// 18.75% of h/U in LDS). Read banks: 2-way max (free on CDNA4).
#define HS_ROW 1152
// phase-A x-tile rows: 256 + margin (row-constant offset, injective)
#define XS_STRIDE 280
// phase-A W-slice rows: 256 + margin (row-constant offset, injective)
#define WL_STRIDE 284

// sA: max(16*1152, 4*16*280)=18432 ; sB: max(16*1152, 64*284)=18432
// red: 8*16*16=2048 ; total = 38912 floats = 155648 B (<= 160 KiB, 1 block/CU)

__device__ __forceinline__ void group_barrier(unsigned* cnt, unsigned* gen) {
  __syncthreads();
  if (threadIdx.x == 0) {
    unsigned g = __hip_atomic_load(gen, __ATOMIC_RELAXED, __HIP_MEMORY_SCOPE_AGENT);
    unsigned a = __hip_atomic_fetch_add(cnt, 1u, __ATOMIC_ACQ_REL, __HIP_MEMORY_SCOPE_AGENT);
    if (a == 63u) {
      __hip_atomic_store(cnt, 0u, __ATOMIC_RELAXED, __HIP_MEMORY_SCOPE_AGENT);
      __hip_atomic_fetch_add(gen, 1u, __ATOMIC_ACQ_REL, __HIP_MEMORY_SCOPE_AGENT);
    } else {
      // timeout valve: wrong-answer instead of hard hang if something breaks
      for (long spin = 0; spin < (long)1 << 28; ++spin) {
        if (__hip_atomic_load(gen, __ATOMIC_ACQUIRE, __HIP_MEMORY_SCOPE_AGENT) != g) break;
        __builtin_amdgcn_s_sleep(1);
      }
    }
  }
  __syncthreads();
}

extern "C" __global__ void __launch_bounds__(512, 1)
rnn_scan_kernel(const float* __restrict__ x, const float* __restrict__ W,
                const float* __restrict__ U, const float* __restrict__ bb,
                float* __restrict__ hbuf, float* __restrict__ xwbuf,
                unsigned* __restrict__ bar, int Tc)
{
  __shared__ float sA[18432];            // union: h-tile (RNN) | x-tiles (phase A)
  __shared__ float sB[18432];            // union: U-slice (RNN) | W-slice (phase A)
  __shared__ float red[8][16][16];       // cross-wave partial reduction

  const int tid  = threadIdx.x;
  const int bid  = blockIdx.x;
  const int r    = bid >> 6;             // independent group (batch row-tile) 0..3
  const int q    = bid & 63;             // within-group id
  const int c0   = q << 4;               // RNN output column base (16 cols)
  const int w    = tid >> 6;             // wave 0..7
  const int lane = tid & 63;

  unsigned* cnt = bar + r * 128;
  unsigned* gen = cnt + 64;

  // ---- phase-A (xW precompute) mapping: block=(tsub,cg), wave covers 16x32, 2 waves/t ----
  const int tsub = q >> 4, cg = q & 15;
  const int a_tw = w >> 1, a_jh = w & 1;
  const int a_kg = lane >> 5;            // 2-way K split (128 each)
  const int a_pi = (lane >> 3) & 3;      // 4 row positions (4 rows each)
  const int a_pj = lane & 7;             // 8 col positions (4 cols each)
  const int a_jl = a_jh * 32 + a_pj * 4; // local col base within 64
  const int a_jglob = cg * 64 + a_jl;
  float4 a_bias = *(const float4*)(bb + a_jglob);

  // ---- RNN mapping: wave w covers K slice [w*128,+128), lane = kg(4) x it(4) x jt(4) ----
  const int r_kg = lane >> 4;
  const int r_it = (lane >> 2) & 3;
  const int r_jt = lane & 3;
  const int hxor = r_it << 3;            // XOR key for ha rows (bits 3-4)
  const int uxor = r_jt << 3;            // XOR key for ub rows

  const int nchunk = CT / Tc;
  const int tquarter = Tc >> 2;

  for (int chunk = 0; chunk < nchunk; ++chunk) {
    // ===== stage W slice (64 cols, transposed) into sB: wl[jl][k] =====
    __syncthreads();
    for (int f = tid; f < 4096; f += 512) {
      int kk = f >> 4, seg = f & 15;
      float4 v = *(const float4*)(W + (size_t)kk * CH + cg * 64 + seg * 4);
      float* wrow = sB + (size_t)(seg * 4) * WL_STRIDE + kk + (seg & 7) * 4;
      wrow[0 * WL_STRIDE] = v.x;
      wrow[1 * WL_STRIDE] = v.y;
      wrow[2 * WL_STRIDE] = v.z;
      wrow[3 * WL_STRIDE] = v.w;
    }

    // ===== phase A: xwbuf[t][b][j] = x[b,t,:] @ W + bias, for this chunk =====
    for (int tb = 0; tb < tquarter; tb += 4) {
      int nt = tquarter - tb; if (nt > 4) nt = 4;
      __syncthreads();
      for (int f = tid; f < nt * 1024; f += 512) {   // float4 count
        int tw = f >> 10, rem = f & 1023;
        int row = rem >> 6, col = (rem & 63) * 4;
        int t = chunk * Tc + tsub * tquarter + tb + tw;
        float4 v = *(const float4*)(x + ((size_t)(r * 16 + row) * CT + t) * CD + col);
        *(float4*)(sA + (size_t)(tw * 16 + row) * XS_STRIDE + col + ((row >> 2) & 3) * 8) = v;
      }
      __syncthreads();
      if (a_tw < nt) {
        int tloc = tsub * tquarter + tb + a_tw;
        float acc[4][4];
        #pragma unroll
        for (int i2 = 0; i2 < 4; ++i2)
          #pragma unroll
          for (int j2 = 0; j2 < 4; ++j2) acc[i2][j2] = 0.f;
        const float* xbase = sA + (size_t)(a_tw * 16 + a_pi * 4) * XS_STRIDE + a_kg * 128 + a_pi * 8;
        const float* wbase = sB + (size_t)a_jl * WL_STRIDE + a_kg * 128 + a_pj * 4;
        #pragma unroll 2
        for (int u = 0; u < 128; u += 4) {
          float4 ha[4], wb[4];
          #pragma unroll
          for (int di = 0; di < 4; ++di) ha[di] = *(const float4*)(xbase + (size_t)di * XS_STRIDE + u);
          #pragma unroll
          for (int dj = 0; dj < 4; ++dj) wb[dj] = *(const float4*)(wbase + (size_t)dj * WL_STRIDE + u);
          #pragma unroll
          for (int di = 0; di < 4; ++di)
            #pragma unroll
            for (int dj = 0; dj < 4; ++dj)
              acc[di][dj] += ha[di].x * wb[dj].x + ha[di].y * wb[dj].y
                           + ha[di].z * wb[dj].z + ha[di].w * wb[dj].w;
        }
        #pragma unroll
        for (int di = 0; di < 4; ++di)
          #pragma unroll
          for (int dj = 0; dj < 4; ++dj)
            acc[di][dj] += __shfl_xor(acc[di][dj], 32, 64);
        if (a_kg == 0) {
          size_t obase = (size_t)tloc * (CB * CH) + (size_t)(r * 16 + a_pi * 4) * CH + a_jglob;
          #pragma unroll
          for (int di = 0; di < 4; ++di) {
            float4 o;
            o.x = acc[di][0] + a_bias.x;
            o.y = acc[di][1] + a_bias.y;
            o.z = acc[di][2] + a_bias.z;
            o.w = acc[di][3] + a_bias.w;
            *(float4*)(xwbuf + obase + (size_t)di * CH) = o;
          }
        }
      }
      __syncthreads();
    }

    // ===== stage U slice (16 cols, transposed) into sB: ul[j][chunk36 ^ swz] =====
    __syncthreads();
    {
      int kk = tid >> 4, j = tid & 15;          // kk 0..31, j 0..15
      const int jx = ((j >> 2) & 3) << 3;
      float* urow = sB + (size_t)j * HS_ROW + (kk ^ jx);
      const float* usrc = U + (size_t)kk * CH + c0 + j;
      #pragma unroll 4
      for (int m = 0; m < 32; ++m) {
        urow[m * 36] = usrc[(size_t)m * 32 * CH];
      }
    }
    group_barrier(cnt, gen);   // xwbuf chunk visible to whole group

    // ===== RNN steps for this chunk =====
    for (int tc = 0; tc < Tc; ++tc) {
      int g = chunk * Tc + tc;
      const float* hb_r = hbuf + (size_t)(g & 1) * (CB * CH);
      float*       hb_w = hbuf + (size_t)((g & 1) ^ 1) * (CB * CH);
      if (g > 0) {
        // stage h tile (16 rows x 1024) -> padded+XOR layout
        for (int f = tid; f < 4096; f += 512) {
          int row = f >> 8, col = (f & 255) * 4;
          float4 v = *(const float4*)(hb_r + (size_t)(r * 16 + row) * CH + col);
          int rsw = ((row >> 2) & 3) << 3;
          *(float4*)(sA + (size_t)row * HS_ROW + (col >> 5) * 36 + ((col & 31) ^ rsw)) = v;
        }
        __syncthreads();
        float acc[4][4];
        #pragma unroll
        for (int i2 = 0; i2 < 4; ++i2)
          #pragma unroll
          for (int j2 = 0; j2 < 4; ++j2) acc[i2][j2] = 0.f;
        const float* habase = sA + (size_t)(r_it * 4) * HS_ROW + (w * 4 + r_kg) * 36;
        const float* ubbase = sB + (size_t)(r_jt * 4) * HS_ROW + (w * 4 + r_kg) * 36;
        #pragma unroll
        for (int u = 0; u < 32; u += 4) {
          float4 ha[4], ub[4];
          #pragma unroll
          for (int di = 0; di < 4; ++di) ha[di] = *(const float4*)(habase + (size_t)di * HS_ROW + (u ^ hxor));
          #pragma unroll
          for (int dj = 0; dj < 4; ++dj) ub[dj] = *(const float4*)(ubbase + (size_t)dj * HS_ROW + (u ^ uxor));
          #pragma unroll
          for (int di = 0; di < 4; ++di)
            #pragma unroll
            for (int dj = 0; dj < 4; ++dj)
              acc[di][dj] += ha[di].x * ub[dj].x + ha[di].y * ub[dj].y
                           + ha[di].z * ub[dj].z + ha[di].w * ub[dj].w;
        }
        #pragma unroll
        for (int di = 0; di < 4; ++di)
          #pragma unroll
          for (int dj = 0; dj < 4; ++dj) {
            float v = acc[di][dj];
            v += __shfl_xor(v, 16, 64);
            v += __shfl_xor(v, 32, 64);
            acc[di][dj] = v;
          }
        if (lane < 16) {
          #pragma unroll
          for (int di = 0; di < 4; ++di) {
            float4 o; o.x = acc[di][0]; o.y = acc[di][1]; o.z = acc[di][2]; o.w = acc[di][3];
            *(float4*)&red[w][r_it * 4 + di][r_jt * 4] = o;
          }
        }
        __syncthreads();
      }
      if (tid < 256) {
        int i = tid >> 4, j = tid & 15;
        float s = 0.f;
        if (g > 0) {
          #pragma unroll
          for (int ww = 0; ww < 8; ++ww) s += red[ww][i][j];
        }
        float z = xwbuf[(size_t)tc * (CB * CH) + (size_t)(r * 16 + i) * CH + c0 + j] + s;
        hb_w[(size_t)(r * 16 + i) * CH + c0 + j] = tanhf(z);
      }
      group_barrier(cnt, gen);
    }
  }
}

// ===== logits: out[64,32000] = hT @ Wd + bd ; one wave computes a 64x64 tile =====
extern "C" __global__ void __launch_bounds__(64, 1)
logits_kernel(const float* __restrict__ hfin, const float* __restrict__ Wd,
              const float* __restrict__ bd, float* __restrict__ out)
{
  __shared__ float al[64][68];   // hT chunk, transposed: al[k][row]
  __shared__ float wl[64][68];   // Wd chunk: wl[k][col]
  const int n0 = blockIdx.x * 64;
  const int lane = threadIdx.x;
  const int pi = lane >> 3, pj = lane & 7;
  float acc[8][8];
  #pragma unroll
  for (int a = 0; a < 8; ++a)
    #pragma unroll
    for (int bq = 0; bq < 8; ++bq) acc[a][bq] = 0.f;

  for (int k0 = 0; k0 < CH; k0 += 64) {
    __syncthreads();
    #pragma unroll
    for (int p = 0; p < 16; ++p) {
      int row = p * 4 + (lane >> 4);
      int seg = lane & 15;
      float4 v = *(const float4*)(hfin + (size_t)row * CH + k0 + seg * 4);
      al[seg * 4 + 0][row] = v.x;
      al[seg * 4 + 1][row] = v.y;
      al[seg * 4 + 2][row] = v.z;
      al[seg * 4 + 3][row] = v.w;
    }
    #pragma unroll
    for (int p = 0; p < 16; ++p) {
      int f = p * 64 + lane;
      int kk = f >> 4, seg = f & 15;
      *(float4*)&wl[kk][seg * 4] = *(const float4*)(Wd + (size_t)(k0 + kk) * CV + n0 + seg * 4);
    }
    __syncthreads();
    #pragma unroll 2
    for (int kk = 0; kk < 64; ++kk) {
      float av[8], bv[8];
      *(float4*)&av[0] = *(const float4*)&al[kk][pi * 8];
      *(float4*)&av[4] = *(const float4*)&al[kk][pi * 8 + 4];
      *(float4*)&bv[0] = *(const float4*)&wl[kk][pj * 8];
      *(float4*)&bv[4] = *(const float4*)&wl[kk][pj * 8 + 4];
      #pragma unroll
      for (int a = 0; a < 8; ++a)
        #pragma unroll
        for (int bq = 0; bq < 8; ++bq)
          acc[a][bq] += av[a] * bv[bq];
    }
  }
  float bdv[8];
  *(float4*)&bdv[0] = *(const float4*)(bd + n0 + pj * 8);
  *(float4*)&bdv[4] = *(const float4*)(bd + n0 + pj * 8 + 4);
  #pragma unroll
  for (int a = 0; a < 8; ++a) {
    int row = pi * 8 + a;
    float4 o0, o1;
    o0.x = acc[a][0] + bdv[0]; o0.y = acc[a][1] + bdv[1];
    o0.z = acc[a][2] + bdv[2]; o0.w = acc[a][3] + bdv[3];
    o1.x = acc[a][4] + bdv[4]; o1.y = acc[a][5] + bdv[5];
    o1.z = acc[a][6] + bdv[6]; o1.w = acc[a][7] + bdv[7];
    *(float4*)(out + (size_t)row * CV + n0 + pj * 8) = o0;
    *(float4*)(out + (size_t)row * CV + n0 + pj * 8 + 4) = o1;
  }
}

// ===== softmax in place over each row of out[64,32000] =====
extern "C" __global__ void __launch_bounds__(256)
softmax_kernel(float* __restrict__ out)
{
  __shared__ float red[256];
  const int row = blockIdx.x;
  const int tid = threadIdx.x;
  float* p = out + (size_t)row * CV;
  float m = -3.4e38f;
  for (int i = tid; i < CV; i += 256) m = fmaxf(m, p[i]);
  red[tid] = m;
  __syncthreads();
  for (int s = 128; s > 0; s >>= 1) {
    if (tid < s) red[tid] = fmaxf(red[tid], red[tid + s]);
    __syncthreads();
  }
  m = red[0];
  __syncthreads();
  float sum = 0.f;
  for (int i = tid; i < CV; i += 256) {
    float e = expf(p[i] - m);
    p[i] = e;
    sum += e;
  }
  red[tid] = sum;
  __syncthreads();
  for (int s = 128; s > 0; s >>= 1) {
    if (tid < s) red[tid] = red[tid] + red[tid + s];
    __syncthreads();
  }
  float inv = 1.f / red[0];
  for (int i = tid; i < CV; i += 256) p[i] *= inv;
}

extern "C" __global__ void init_bar(unsigned* bar) {
  bar[threadIdx.x] = 0u;   // 1024 uints = 4 KiB barrier area
}

extern "C" void kernel_launch(void* const* d_in, const int* in_sizes, int n_in,
                              void* d_out, int out_size, void* d_ws, size_t ws_size,
                              hipStream_t stream) {
  const float* x  = (const float*)d_in[0];
  const float* W  = (const float*)d_in[1];
  const float* U  = (const float*)d_in[2];
  const float* bb = (const float*)d_in[3];
  const float* Wd = (const float*)d_in[4];
  const float* bd = (const float*)d_in[5];
  float* out = (float*)d_out;

  char* ws = (char*)d_ws;
  unsigned* bar = (unsigned*)ws;
  float* hbuf  = (float*)(ws + 4096);
  float* xwbuf = (float*)(ws + 4096 + (size_t)2 * CB * CH * sizeof(float));

  // largest xW chunk that fits the workspace (Tc divides 512, multiple of 4)
  const int cands[7] = {512, 256, 128, 64, 32, 16, 8};
  int Tc = 4;
  for (int ci = 0; ci < 7; ++ci) {
    size_t need = 4096 + (size_t)2 * CB * CH * 4 + (size_t)cands[ci] * CB * CH * 4;
    if (need <= ws_size) { Tc = cands[ci]; break; }
  }

  hipLaunchKernelGGL(init_bar, dim3(1), dim3(1024), 0, stream, bar);

  void* args[8];
  args[0] = (void*)&x;     args[1] = (void*)&W;     args[2] = (void*)&U;   args[3] = (void*)&bb;
  args[4] = (void*)&hbuf;  args[5] = (void*)&xwbuf; args[6] = (void*)&bar; args[7] = (void*)&Tc;
  hipLaunchCooperativeKernel((void*)rnn_scan_kernel, dim3(256), dim3(512), args, 0, stream);

  // final h state lives in hbuf[0] (T=512 even)
  hipLaunchKernelGGL(logits_kernel, dim3(CV / 64), dim3(64), 0, stream, hbuf, Wd, bd, out);
  hipLaunchKernelGGL(softmax_kernel, dim3(CB), dim3(256), 0, stream, out);
}

// Round 3
// 9331.663 us; speedup vs baseline: 1.2778x; 1.2778x over previous
//
#include <hip/hip_runtime.h>
#include <math.h>

#define CB 64
#define CT 512
#define CD 256
#define CH 1024
#define CV 32000

// ---- LDS layouts ----
// RNN h-tile / U-slice: row stride 1152 floats; each 32-float K-chunk padded
// to 36 floats; within-chunk float4 slot XOR-swizzled by ((row>>2)&3)<<3.
// XOR swizzle is bijective. Read banks: 2-way max (free on CDNA4).
#define HS_ROW 1152
#define XS_STRIDE 280
#define WL_STRIDE 284

// Flag barrier: one 128B-padded flag per block per group. Round-2 counters
// showed the single-counter barrier cost ~21us/step (64 serialized cross-XCD
// RMWs on one line; VALUBusy=11%). Flags: parallel stores + one wave polling
// 64 independent lines in parallel -> ~one memory latency per poll iter.
#define FLAG_STRIDE 32   // uints (128 B)

__device__ __forceinline__ void flag_barrier(unsigned* flags, int q, unsigned target) {
  __syncthreads();   // drains every wave's global writes (vmcnt(0) before s_barrier)
  if (threadIdx.x < 64) {
    if ((int)threadIdx.x == q)
      __hip_atomic_store(flags + (size_t)q * FLAG_STRIDE, target,
                         __ATOMIC_RELEASE, __HIP_MEMORY_SCOPE_AGENT);
    const unsigned* f = flags + (size_t)threadIdx.x * FLAG_STRIDE;
    long spin = 0;
    unsigned v;
    do {
      v = __hip_atomic_load(f, __ATOMIC_RELAXED, __HIP_MEMORY_SCOPE_AGENT);
    } while (__any((int)(v < target)) && ++spin < (1L << 27));  // valve: no hard hang
    __threadfence();  // acquire side: invalidate stale L1/L2 before re-reading h/xw
  }
  __syncthreads();
}

extern "C" __global__ void __launch_bounds__(512, 1)
rnn_scan_kernel(const float* __restrict__ x, const float* __restrict__ W,
                const float* __restrict__ U, const float* __restrict__ bb,
                float* __restrict__ hbuf, float* __restrict__ xwbuf,
                unsigned* __restrict__ bar, int Tc)
{
  __shared__ float sA[18432];            // union: h-tile (RNN) | x-tiles (phase A)
  __shared__ float sB[18432];            // union: U-slice (RNN) | W-slice (phase A)
  __shared__ float red[8][16][16];       // cross-wave partial reduction

  const int tid  = threadIdx.x;
  const int bid  = blockIdx.x;
  const int r    = bid >> 6;             // independent group (batch row-tile) 0..3
  const int q    = bid & 63;             // within-group id
  const int c0   = q << 4;               // RNN output column base (16 cols)
  const int w    = tid >> 6;             // wave 0..7
  const int lane = tid & 63;

  unsigned* flags = bar + (size_t)r * 64 * FLAG_STRIDE;
  unsigned epoch = 0;

  // ---- phase-A (xW precompute) mapping: block=(tsub,cg), wave covers 16x32, 2 waves/t ----
  const int tsub = q >> 4, cg = q & 15;
  const int a_tw = w >> 1, a_jh = w & 1;
  const int a_kg = lane >> 5;            // 2-way K split (128 each)
  const int a_pi = (lane >> 3) & 3;      // 4 row positions (4 rows each)
  const int a_pj = lane & 7;             // 8 col positions (4 cols each)
  const int a_jl = a_jh * 32 + a_pj * 4; // local col base within 64
  const int a_jglob = cg * 64 + a_jl;
  float4 a_bias = *(const float4*)(bb + a_jglob);

  // ---- RNN mapping: wave w covers K slice [w*128,+128), lane = kg(4) x it(4) x jt(4) ----
  const int r_kg = lane >> 4;
  const int r_it = (lane >> 2) & 3;
  const int r_jt = lane & 3;
  const int hxor = r_it << 3;            // XOR key for ha rows (bits 3-4)
  const int uxor = r_jt << 3;            // XOR key for ub rows

  const int nchunk = CT / Tc;
  const int tquarter = Tc >> 2;

  for (int chunk = 0; chunk < nchunk; ++chunk) {
    // ===== stage W slice (64 cols, transposed) into sB: wl[jl][k] =====
    __syncthreads();
    for (int f = tid; f < 4096; f += 512) {
      int kk = f >> 4, seg = f & 15;
      float4 v = *(const float4*)(W + (size_t)kk * CH + cg * 64 + seg * 4);
      float* wrow = sB + (size_t)(seg * 4) * WL_STRIDE + kk + (seg & 7) * 4;
      wrow[0 * WL_STRIDE] = v.x;
      wrow[1 * WL_STRIDE] = v.y;
      wrow[2 * WL_STRIDE] = v.z;
      wrow[3 * WL_STRIDE] = v.w;
    }

    // ===== phase A: xwbuf[t][b][j] = x[b,t,:] @ W + bias, for this chunk =====
    for (int tb = 0; tb < tquarter; tb += 4) {
      int nt = tquarter - tb; if (nt > 4) nt = 4;
      __syncthreads();
      for (int f = tid; f < nt * 1024; f += 512) {   // float4 count
        int tw = f >> 10, rem = f & 1023;
        int row = rem >> 6, col = (rem & 63) * 4;
        int t = chunk * Tc + tsub * tquarter + tb + tw;
        float4 v = *(const float4*)(x + ((size_t)(r * 16 + row) * CT + t) * CD + col);
        *(float4*)(sA + (size_t)(tw * 16 + row) * XS_STRIDE + col + ((row >> 2) & 3) * 8) = v;
      }
      __syncthreads();
      if (a_tw < nt) {
        int tloc = tsub * tquarter + tb + a_tw;
        float acc[4][4];
        #pragma unroll
        for (int i2 = 0; i2 < 4; ++i2)
          #pragma unroll
          for (int j2 = 0; j2 < 4; ++j2) acc[i2][j2] = 0.f;
        const float* xbase = sA + (size_t)(a_tw * 16 + a_pi * 4) * XS_STRIDE + a_kg * 128 + a_pi * 8;
        const float* wbase = sB + (size_t)a_jl * WL_STRIDE + a_kg * 128 + a_pj * 4;
        #pragma unroll 2
        for (int u = 0; u < 128; u += 4) {
          float4 ha[4], wb[4];
          #pragma unroll
          for (int di = 0; di < 4; ++di) ha[di] = *(const float4*)(xbase + (size_t)di * XS_STRIDE + u);
          #pragma unroll
          for (int dj = 0; dj < 4; ++dj) wb[dj] = *(const float4*)(wbase + (size_t)dj * WL_STRIDE + u);
          #pragma unroll
          for (int di = 0; di < 4; ++di)
            #pragma unroll
            for (int dj = 0; dj < 4; ++dj)
              acc[di][dj] += ha[di].x * wb[dj].x + ha[di].y * wb[dj].y
                           + ha[di].z * wb[dj].z + ha[di].w * wb[dj].w;
        }
        #pragma unroll
        for (int di = 0; di < 4; ++di)
          #pragma unroll
          for (int dj = 0; dj < 4; ++dj)
            acc[di][dj] += __shfl_xor(acc[di][dj], 32, 64);
        if (a_kg == 0) {
          size_t obase = (size_t)tloc * (CB * CH) + (size_t)(r * 16 + a_pi * 4) * CH + a_jglob;
          #pragma unroll
          for (int di = 0; di < 4; ++di) {
            float4 o;
            o.x = acc[di][0] + a_bias.x;
            o.y = acc[di][1] + a_bias.y;
            o.z = acc[di][2] + a_bias.z;
            o.w = acc[di][3] + a_bias.w;
            *(float4*)(xwbuf + obase + (size_t)di * CH) = o;
          }
        }
      }
      __syncthreads();
    }

    // ===== stage U slice (16 cols, transposed) into sB: ul[j][chunk36 ^ swz] =====
    __syncthreads();
    {
      int kk = tid >> 4, j = tid & 15;          // kk 0..31, j 0..15
      const int jx = ((j >> 2) & 3) << 3;
      float* urow = sB + (size_t)j * HS_ROW + (kk ^ jx);
      const float* usrc = U + (size_t)kk * CH + c0 + j;
      #pragma unroll 4
      for (int m = 0; m < 32; ++m) {
        urow[m * 36] = usrc[(size_t)m * 32 * CH];
      }
    }
    flag_barrier(flags, q, ++epoch);   // xwbuf chunk visible to whole group

    // ===== RNN steps for this chunk =====
    for (int tc = 0; tc < Tc; ++tc) {
      int g = chunk * Tc + tc;
      const float* hb_r = hbuf + (size_t)(g & 1) * (CB * CH);
      float*       hb_w = hbuf + (size_t)((g & 1) ^ 1) * (CB * CH);
      if (g > 0) {
        // stage h tile (16 rows x 1024) -> padded+XOR layout
        for (int f = tid; f < 4096; f += 512) {
          int row = f >> 8, col = (f & 255) * 4;
          float4 v = *(const float4*)(hb_r + (size_t)(r * 16 + row) * CH + col);
          int rsw = ((row >> 2) & 3) << 3;
          *(float4*)(sA + (size_t)row * HS_ROW + (col >> 5) * 36 + ((col & 31) ^ rsw)) = v;
        }
        __syncthreads();
        float acc[4][4];
        #pragma unroll
        for (int i2 = 0; i2 < 4; ++i2)
          #pragma unroll
          for (int j2 = 0; j2 < 4; ++j2) acc[i2][j2] = 0.f;
        const float* habase = sA + (size_t)(r_it * 4) * HS_ROW + (w * 4 + r_kg) * 36;
        const float* ubbase = sB + (size_t)(r_jt * 4) * HS_ROW + (w * 4 + r_kg) * 36;
        #pragma unroll
        for (int u = 0; u < 32; u += 4) {
          float4 ha[4], ub[4];
          #pragma unroll
          for (int di = 0; di < 4; ++di) ha[di] = *(const float4*)(habase + (size_t)di * HS_ROW + (u ^ hxor));
          #pragma unroll
          for (int dj = 0; dj < 4; ++dj) ub[dj] = *(const float4*)(ubbase + (size_t)dj * HS_ROW + (u ^ uxor));
          #pragma unroll
          for (int di = 0; di < 4; ++di)
            #pragma unroll
            for (int dj = 0; dj < 4; ++dj)
              acc[di][dj] += ha[di].x * ub[dj].x + ha[di].y * ub[dj].y
                           + ha[di].z * ub[dj].z + ha[di].w * ub[dj].w;
        }
        #pragma unroll
        for (int di = 0; di < 4; ++di)
          #pragma unroll
          for (int dj = 0; dj < 4; ++dj) {
            float v = acc[di][dj];
            v += __shfl_xor(v, 16, 64);
            v += __shfl_xor(v, 32, 64);
            acc[di][dj] = v;
          }
        if (lane < 16) {
          #pragma unroll
          for (int di = 0; di < 4; ++di) {
            float4 o; o.x = acc[di][0]; o.y = acc[di][1]; o.z = acc[di][2]; o.w = acc[di][3];
            *(float4*)&red[w][r_it * 4 + di][r_jt * 4] = o;
          }
        }
        __syncthreads();
      }
      if (tid < 256) {
        int i = tid >> 4, j = tid & 15;
        float s = 0.f;
        if (g > 0) {
          #pragma unroll
          for (int ww = 0; ww < 8; ++ww) s += red[ww][i][j];
        }
        float z = xwbuf[(size_t)tc * (CB * CH) + (size_t)(r * 16 + i) * CH + c0 + j] + s;
        hb_w[(size_t)(r * 16 + i) * CH + c0 + j] = tanhf(z);
      }
      flag_barrier(flags, q, ++epoch);
    }
  }
}

// ===== logits: out[64,32000] = hT @ Wd + bd ; one wave computes a 64x64 tile =====
extern "C" __global__ void __launch_bounds__(64, 1)
logits_kernel(const float* __restrict__ hfin, const float* __restrict__ Wd,
              const float* __restrict__ bd, float* __restrict__ out)
{
  __shared__ float al[64][68];   // hT chunk, transposed: al[k][row]
  __shared__ float wl[64][68];   // Wd chunk: wl[k][col]
  const int n0 = blockIdx.x * 64;
  const int lane = threadIdx.x;
  const int pi = lane >> 3, pj = lane & 7;
  float acc[8][8];
  #pragma unroll
  for (int a = 0; a < 8; ++a)
    #pragma unroll
    for (int bq = 0; bq < 8; ++bq) acc[a][bq] = 0.f;

  for (int k0 = 0; k0 < CH; k0 += 64) {
    __syncthreads();
    #pragma unroll
    for (int p = 0; p < 16; ++p) {
      int row = p * 4 + (lane >> 4);
      int seg = lane & 15;
      float4 v = *(const float4*)(hfin + (size_t)row * CH + k0 + seg * 4);
      al[seg * 4 + 0][row] = v.x;
      al[seg * 4 + 1][row] = v.y;
      al[seg * 4 + 2][row] = v.z;
      al[seg * 4 + 3][row] = v.w;
    }
    #pragma unroll
    for (int p = 0; p < 16; ++p) {
      int f = p * 64 + lane;
      int kk = f >> 4, seg = f & 15;
      *(float4*)&wl[kk][seg * 4] = *(const float4*)(Wd + (size_t)(k0 + kk) * CV + n0 + seg * 4);
    }
    __syncthreads();
    #pragma unroll 2
    for (int kk = 0; kk < 64; ++kk) {
      float av[8], bv[8];
      *(float4*)&av[0] = *(const float4*)&al[kk][pi * 8];
      *(float4*)&av[4] = *(const float4*)&al[kk][pi * 8 + 4];
      *(float4*)&bv[0] = *(const float4*)&wl[kk][pj * 8];
      *(float4*)&bv[4] = *(const float4*)&wl[kk][pj * 8 + 4];
      #pragma unroll
      for (int a = 0; a < 8; ++a)
        #pragma unroll
        for (int bq = 0; bq < 8; ++bq)
          acc[a][bq] += av[a] * bv[bq];
    }
  }
  float bdv[8];
  *(float4*)&bdv[0] = *(const float4*)(bd + n0 + pj * 8);
  *(float4*)&bdv[4] = *(const float4*)(bd + n0 + pj * 8 + 4);
  #pragma unroll
  for (int a = 0; a < 8; ++a) {
    int row = pi * 8 + a;
    float4 o0, o1;
    o0.x = acc[a][0] + bdv[0]; o0.y = acc[a][1] + bdv[1];
    o0.z = acc[a][2] + bdv[2]; o0.w = acc[a][3] + bdv[3];
    o1.x = acc[a][4] + bdv[4]; o1.y = acc[a][5] + bdv[5];
    o1.z = acc[a][6] + bdv[6]; o1.w = acc[a][7] + bdv[7];
    *(float4*)(out + (size_t)row * CV + n0 + pj * 8) = o0;
    *(float4*)(out + (size_t)row * CV + n0 + pj * 8 + 4) = o1;
  }
}

// ===== softmax in place over each row of out[64,32000] =====
extern "C" __global__ void __launch_bounds__(256)
softmax_kernel(float* __restrict__ out)
{
  __shared__ float red[256];
  const int row = blockIdx.x;
  const int tid = threadIdx.x;
  float* p = out + (size_t)row * CV;
  float m = -3.4e38f;
  for (int i = tid; i < CV; i += 256) m = fmaxf(m, p[i]);
  red[tid] = m;
  __syncthreads();
  for (int s = 128; s > 0; s >>= 1) {
    if (tid < s) red[tid] = fmaxf(red[tid], red[tid + s]);
    __syncthreads();
  }
  m = red[0];
  __syncthreads();
  float sum = 0.f;
  for (int i = tid; i < CV; i += 256) {
    float e = expf(p[i] - m);
    p[i] = e;
    sum += e;
  }
  red[tid] = sum;
  __syncthreads();
  for (int s = 128; s > 0; s >>= 1) {
    if (tid < s) red[tid] = red[tid] + red[tid + s];
    __syncthreads();
  }
  float inv = 1.f / red[0];
  for (int i = tid; i < CV; i += 256) p[i] *= inv;
}

extern "C" __global__ void init_bar(unsigned* bar) {
  bar[(size_t)blockIdx.x * 1024 + threadIdx.x] = 0u;   // 4 groups * 64 flags * 128B
}

extern "C" void kernel_launch(void* const* d_in, const int* in_sizes, int n_in,
                              void* d_out, int out_size, void* d_ws, size_t ws_size,
                              hipStream_t stream) {
  const float* x  = (const float*)d_in[0];
  const float* W  = (const float*)d_in[1];
  const float* U  = (const float*)d_in[2];
  const float* bb = (const float*)d_in[3];
  const float* Wd = (const float*)d_in[4];
  const float* bd = (const float*)d_in[5];
  float* out = (float*)d_out;

  char* ws = (char*)d_ws;
  unsigned* bar = (unsigned*)ws;                      // 32 KiB flag area
  float* hbuf  = (float*)(ws + 32768);
  float* xwbuf = (float*)(ws + 32768 + (size_t)2 * CB * CH * sizeof(float));

  // largest xW chunk that fits the workspace (Tc divides 512, multiple of 4)
  const int cands[7] = {512, 256, 128, 64, 32, 16, 8};
  int Tc = 4;
  for (int ci = 0; ci < 7; ++ci) {
    size_t need = 32768 + (size_t)2 * CB * CH * 4 + (size_t)cands[ci] * CB * CH * 4;
    if (need <= ws_size) { Tc = cands[ci]; break; }
  }

  hipLaunchKernelGGL(init_bar, dim3(8), dim3(1024), 0, stream, bar);

  void* args[8];
  args[0] = (void*)&x;     args[1] = (void*)&W;     args[2] = (void*)&U;   args[3] = (void*)&bb;
  args[4] = (void*)&hbuf;  args[5] = (void*)&xwbuf; args[6] = (void*)&bar; args[7] = (void*)&Tc;
  hipLaunchCooperativeKernel((void*)rnn_scan_kernel, dim3(256), dim3(512), args, 0, stream);

  // final h state lives in hbuf[0] (T=512 even)
  hipLaunchKernelGGL(logits_kernel, dim3(CV / 64), dim3(64), 0, stream, hbuf, Wd, bd, out);
  hipLaunchKernelGGL(softmax_kernel, dim3(CB), dim3(256), 0, stream, out);
}

// Round 4
// 5679.364 us; speedup vs baseline: 2.0995x; 1.6431x over previous
//
#include <hip/hip_runtime.h>
#include <math.h>
#include <string.h>

#define CB 64
#define CT 512
#define CD 256
#define CH 1024
#define CV 32000

// ---- LDS layouts ----
// RNN h-tile / U-slice: row stride 1152 floats; each 32-float K-chunk padded
// to 36 floats; within-chunk float4 slot XOR-swizzled by ((row>>2)&3)<<3.
// XOR swizzle is bijective. Read banks: 2-way max (free on CDNA4).
#define HS_ROW 1152
#define XS_STRIDE 280
#define WL_STRIDE 284

#define FLAG_STRIDE 32   // uints (128 B) per flag

// Fenced barrier (chunk boundaries only): release store emits wbl2, acquire
// fence emits buffer_inv -> makes cached xwbuf writes visible. R3 counters
// showed these L2 maintenance ops at ~13us/step when run per-step; now 9x total.
__device__ __forceinline__ void flag_barrier_fenced(unsigned* flags, int q, unsigned target) {
  __syncthreads();
  if (threadIdx.x < 64) {
    if ((int)threadIdx.x == q)
      __hip_atomic_store(flags + (size_t)q * FLAG_STRIDE, target,
                         __ATOMIC_RELEASE, __HIP_MEMORY_SCOPE_AGENT);
    const unsigned* f = flags + (size_t)threadIdx.x * FLAG_STRIDE;
    long spin = 0;
    unsigned v;
    do {
      v = __hip_atomic_load(f, __ATOMIC_RELAXED, __HIP_MEMORY_SCOPE_AGENT);
    } while (__any((int)(v < target)) && ++spin < (1L << 27));
    __threadfence();
  }
  __syncthreads();
}

// Fence-free step barrier: h data moves via write-through stores (producer)
// and L2-bypassing loads (consumer), so no wbl2/inv needed. __syncthreads
// drains vmcnt(0) per wave -> write-through stores are globally visible
// before the flag store issues.
__device__ __forceinline__ void step_barrier(unsigned* flags, int q, unsigned target) {
  __syncthreads();
  if (threadIdx.x < 64) {
    if ((int)threadIdx.x == q)
      __hip_atomic_store(flags + (size_t)q * FLAG_STRIDE, target,
                         __ATOMIC_RELAXED, __HIP_MEMORY_SCOPE_AGENT);
    __atomic_signal_fence(__ATOMIC_SEQ_CST);   // compiler-only: keep store before poll
    const unsigned* f = flags + (size_t)threadIdx.x * FLAG_STRIDE;
    long spin = 0;
    unsigned v;
    do {
      v = __hip_atomic_load(f, __ATOMIC_RELAXED, __HIP_MEMORY_SCOPE_AGENT);
    } while (__any((int)(v < target)) && ++spin < (1L << 27));
    __atomic_signal_fence(__ATOMIC_ACQUIRE);   // compiler-only: no load hoisting
  }
  __syncthreads();
}

extern "C" __global__ void __launch_bounds__(512, 1)
rnn_scan_kernel(const float* __restrict__ x, const float* __restrict__ W,
                const float* __restrict__ U, const float* __restrict__ bb,
                float* __restrict__ hbuf, float* __restrict__ xwbuf,
                unsigned* __restrict__ bar, int Tc)
{
  __shared__ float sA[18432];            // union: h-tile (RNN) | x-tiles (phase A)
  __shared__ float sB[18432];            // union: U-slice (RNN) | W-slice (phase A)
  __shared__ float red[8][16][16];       // cross-wave partial reduction

  const int tid  = threadIdx.x;
  const int bid  = blockIdx.x;
  const int r    = bid >> 6;             // independent group (batch row-tile) 0..3
  const int q    = bid & 63;             // within-group id
  const int c0   = q << 4;               // RNN output column base (16 cols)
  const int w    = tid >> 6;             // wave 0..7
  const int lane = tid & 63;

  unsigned* flags = bar + (size_t)r * 64 * FLAG_STRIDE;
  unsigned epoch = 0;

  // ---- phase-A (xW precompute) mapping ----
  const int tsub = q >> 4, cg = q & 15;
  const int a_tw = w >> 1, a_jh = w & 1;
  const int a_kg = lane >> 5;
  const int a_pi = (lane >> 3) & 3;
  const int a_pj = lane & 7;
  const int a_jl = a_jh * 32 + a_pj * 4;
  const int a_jglob = cg * 64 + a_jl;
  float4 a_bias = *(const float4*)(bb + a_jglob);

  // ---- RNN mapping ----
  const int r_kg = lane >> 4;
  const int r_it = (lane >> 2) & 3;
  const int r_jt = lane & 3;
  const int hxor = r_it << 3;
  const int uxor = r_jt << 3;

  const int nchunk = CT / Tc;
  const int tquarter = Tc >> 2;

  for (int chunk = 0; chunk < nchunk; ++chunk) {
    // ===== stage W slice (64 cols, transposed) into sB =====
    __syncthreads();
    for (int f = tid; f < 4096; f += 512) {
      int kk = f >> 4, seg = f & 15;
      float4 v = *(const float4*)(W + (size_t)kk * CH + cg * 64 + seg * 4);
      float* wrow = sB + (size_t)(seg * 4) * WL_STRIDE + kk + (seg & 7) * 4;
      wrow[0 * WL_STRIDE] = v.x;
      wrow[1 * WL_STRIDE] = v.y;
      wrow[2 * WL_STRIDE] = v.z;
      wrow[3 * WL_STRIDE] = v.w;
    }

    // ===== phase A: xwbuf[t][b][j] = x[b,t,:] @ W + bias =====
    for (int tb = 0; tb < tquarter; tb += 4) {
      int nt = tquarter - tb; if (nt > 4) nt = 4;
      __syncthreads();
      for (int f = tid; f < nt * 1024; f += 512) {
        int tw = f >> 10, rem = f & 1023;
        int row = rem >> 6, col = (rem & 63) * 4;
        int t = chunk * Tc + tsub * tquarter + tb + tw;
        float4 v = *(const float4*)(x + ((size_t)(r * 16 + row) * CT + t) * CD + col);
        *(float4*)(sA + (size_t)(tw * 16 + row) * XS_STRIDE + col + ((row >> 2) & 3) * 8) = v;
      }
      __syncthreads();
      if (a_tw < nt) {
        int tloc = tsub * tquarter + tb + a_tw;
        float acc[4][4];
        #pragma unroll
        for (int i2 = 0; i2 < 4; ++i2)
          #pragma unroll
          for (int j2 = 0; j2 < 4; ++j2) acc[i2][j2] = 0.f;
        const float* xbase = sA + (size_t)(a_tw * 16 + a_pi * 4) * XS_STRIDE + a_kg * 128 + a_pi * 8;
        const float* wbase = sB + (size_t)a_jl * WL_STRIDE + a_kg * 128 + a_pj * 4;
        #pragma unroll 2
        for (int u = 0; u < 128; u += 4) {
          float4 ha[4], wb[4];
          #pragma unroll
          for (int di = 0; di < 4; ++di) ha[di] = *(const float4*)(xbase + (size_t)di * XS_STRIDE + u);
          #pragma unroll
          for (int dj = 0; dj < 4; ++dj) wb[dj] = *(const float4*)(wbase + (size_t)dj * WL_STRIDE + u);
          #pragma unroll
          for (int di = 0; di < 4; ++di)
            #pragma unroll
            for (int dj = 0; dj < 4; ++dj)
              acc[di][dj] += ha[di].x * wb[dj].x + ha[di].y * wb[dj].y
                           + ha[di].z * wb[dj].z + ha[di].w * wb[dj].w;
        }
        #pragma unroll
        for (int di = 0; di < 4; ++di)
          #pragma unroll
          for (int dj = 0; dj < 4; ++dj)
            acc[di][dj] += __shfl_xor(acc[di][dj], 32, 64);
        if (a_kg == 0) {
          size_t obase = (size_t)tloc * (CB * CH) + (size_t)(r * 16 + a_pi * 4) * CH + a_jglob;
          #pragma unroll
          for (int di = 0; di < 4; ++di) {
            float4 o;
            o.x = acc[di][0] + a_bias.x;
            o.y = acc[di][1] + a_bias.y;
            o.z = acc[di][2] + a_bias.z;
            o.w = acc[di][3] + a_bias.w;
            *(float4*)(xwbuf + obase + (size_t)di * CH) = o;
          }
        }
      }
      __syncthreads();
    }

    // ===== stage U slice (16 cols, transposed) into sB =====
    __syncthreads();
    {
      int kk = tid >> 4, j = tid & 15;
      const int jx = ((j >> 2) & 3) << 3;
      float* urow = sB + (size_t)j * HS_ROW + (kk ^ jx);
      const float* usrc = U + (size_t)kk * CH + c0 + j;
      #pragma unroll 4
      for (int m = 0; m < 32; ++m) {
        urow[m * 36] = usrc[(size_t)m * 32 * CH];
      }
    }
    flag_barrier_fenced(flags, q, ++epoch);   // xwbuf chunk visible (wbl2+inv)

    // ===== RNN steps for this chunk =====
    for (int tc = 0; tc < Tc; ++tc) {
      int g = chunk * Tc + tc;
      const float* hb_r = hbuf + (size_t)(g & 1) * (CB * CH);
      float*       hb_w = hbuf + (size_t)((g & 1) ^ 1) * (CB * CH);
      if (g > 0) {
        // stage h tile (16 rows x 1024) via L2-bypassing 8B coherent loads
        for (int f = tid; f < 8192; f += 512) {
          int row = f >> 9;              // 512 x 8B per row
          int c2  = f & 511;
          int col = c2 << 1;             // even float col
          unsigned long long v = __hip_atomic_load(
              (const unsigned long long*)(hb_r + (size_t)(r * 16 + row) * CH) + c2,
              __ATOMIC_RELAXED, __HIP_MEMORY_SCOPE_AGENT);
          float2 fv;
          __builtin_memcpy(&fv, &v, 8);
          int rsw = ((row >> 2) & 3) << 3;
          *(float2*)(sA + (size_t)row * HS_ROW + (col >> 5) * 36 + ((col & 31) ^ rsw)) = fv;
        }
        __syncthreads();
        float acc[4][4];
        #pragma unroll
        for (int i2 = 0; i2 < 4; ++i2)
          #pragma unroll
          for (int j2 = 0; j2 < 4; ++j2) acc[i2][j2] = 0.f;
        const float* habase = sA + (size_t)(r_it * 4) * HS_ROW + (w * 4 + r_kg) * 36;
        const float* ubbase = sB + (size_t)(r_jt * 4) * HS_ROW + (w * 4 + r_kg) * 36;
        #pragma unroll
        for (int u = 0; u < 32; u += 4) {
          float4 ha[4], ub[4];
          #pragma unroll
          for (int di = 0; di < 4; ++di) ha[di] = *(const float4*)(habase + (size_t)di * HS_ROW + (u ^ hxor));
          #pragma unroll
          for (int dj = 0; dj < 4; ++dj) ub[dj] = *(const float4*)(ubbase + (size_t)dj * HS_ROW + (u ^ uxor));
          #pragma unroll
          for (int di = 0; di < 4; ++di)
            #pragma unroll
            for (int dj = 0; dj < 4; ++dj)
              acc[di][dj] += ha[di].x * ub[dj].x + ha[di].y * ub[dj].y
                           + ha[di].z * ub[dj].z + ha[di].w * ub[dj].w;
        }
        #pragma unroll
        for (int di = 0; di < 4; ++di)
          #pragma unroll
          for (int dj = 0; dj < 4; ++dj) {
            float v = acc[di][dj];
            v += __shfl_xor(v, 16, 64);
            v += __shfl_xor(v, 32, 64);
            acc[di][dj] = v;
          }
        if (lane < 16) {
          #pragma unroll
          for (int di = 0; di < 4; ++di) {
            float4 o; o.x = acc[di][0]; o.y = acc[di][1]; o.z = acc[di][2]; o.w = acc[di][3];
            *(float4*)&red[w][r_it * 4 + di][r_jt * 4] = o;
          }
        }
        __syncthreads();
      }
      if (tid < 256) {
        int i = tid >> 4, j = tid & 15;
        float s = 0.f;
        if (g > 0) {
          #pragma unroll
          for (int ww = 0; ww < 8; ++ww) s += red[ww][i][j];
        }
        float z = xwbuf[(size_t)tc * (CB * CH) + (size_t)(r * 16 + i) * CH + c0 + j] + s;
        // write-through (sc0 sc1) store: globally visible once vmcnt drains
        __hip_atomic_store(hb_w + (size_t)(r * 16 + i) * CH + c0 + j, tanhf(z),
                           __ATOMIC_RELAXED, __HIP_MEMORY_SCOPE_AGENT);
      }
      step_barrier(flags, q, ++epoch);
    }
  }
}

// ===== logits: out[64,32000] = hT @ Wd + bd ; one wave computes a 64x64 tile =====
extern "C" __global__ void __launch_bounds__(64, 1)
logits_kernel(const float* __restrict__ hfin, const float* __restrict__ Wd,
              const float* __restrict__ bd, float* __restrict__ out)
{
  __shared__ float al[64][68];   // hT chunk, transposed: al[k][row]
  __shared__ float wl[64][68];   // Wd chunk: wl[k][col]
  const int n0 = blockIdx.x * 64;
  const int lane = threadIdx.x;
  const int pi = lane >> 3, pj = lane & 7;
  float acc[8][8];
  #pragma unroll
  for (int a = 0; a < 8; ++a)
    #pragma unroll
    for (int bq = 0; bq < 8; ++bq) acc[a][bq] = 0.f;

  for (int k0 = 0; k0 < CH; k0 += 64) {
    __syncthreads();
    #pragma unroll
    for (int p = 0; p < 16; ++p) {
      int row = p * 4 + (lane >> 4);
      int seg = lane & 15;
      float4 v = *(const float4*)(hfin + (size_t)row * CH + k0 + seg * 4);
      al[seg * 4 + 0][row] = v.x;
      al[seg * 4 + 1][row] = v.y;
      al[seg * 4 + 2][row] = v.z;
      al[seg * 4 + 3][row] = v.w;
    }
    #pragma unroll
    for (int p = 0; p < 16; ++p) {
      int f = p * 64 + lane;
      int kk = f >> 4, seg = f & 15;
      *(float4*)&wl[kk][seg * 4] = *(const float4*)(Wd + (size_t)(k0 + kk) * CV + n0 + seg * 4);
    }
    __syncthreads();
    #pragma unroll 2
    for (int kk = 0; kk < 64; ++kk) {
      float av[8], bv[8];
      *(float4*)&av[0] = *(const float4*)&al[kk][pi * 8];
      *(float4*)&av[4] = *(const float4*)&al[kk][pi * 8 + 4];
      *(float4*)&bv[0] = *(const float4*)&wl[kk][pj * 8];
      *(float4*)&bv[4] = *(const float4*)&wl[kk][pj * 8 + 4];
      #pragma unroll
      for (int a = 0; a < 8; ++a)
        #pragma unroll
        for (int bq = 0; bq < 8; ++bq)
          acc[a][bq] += av[a] * bv[bq];
    }
  }
  float bdv[8];
  *(float4*)&bdv[0] = *(const float4*)(bd + n0 + pj * 8);
  *(float4*)&bdv[4] = *(const float4*)(bd + n0 + pj * 8 + 4);
  #pragma unroll
  for (int a = 0; a < 8; ++a) {
    int row = pi * 8 + a;
    float4 o0, o1;
    o0.x = acc[a][0] + bdv[0]; o0.y = acc[a][1] + bdv[1];
    o0.z = acc[a][2] + bdv[2]; o0.w = acc[a][3] + bdv[3];
    o1.x = acc[a][4] + bdv[4]; o1.y = acc[a][5] + bdv[5];
    o1.z = acc[a][6] + bdv[6]; o1.w = acc[a][7] + bdv[7];
    *(float4*)(out + (size_t)row * CV + n0 + pj * 8) = o0;
    *(float4*)(out + (size_t)row * CV + n0 + pj * 8 + 4) = o1;
  }
}

// ===== softmax in place over each row of out[64,32000] =====
extern "C" __global__ void __launch_bounds__(256)
softmax_kernel(float* __restrict__ out)
{
  __shared__ float red[256];
  const int row = blockIdx.x;
  const int tid = threadIdx.x;
  float* p = out + (size_t)row * CV;
  float m = -3.4e38f;
  for (int i = tid; i < CV; i += 256) m = fmaxf(m, p[i]);
  red[tid] = m;
  __syncthreads();
  for (int s = 128; s > 0; s >>= 1) {
    if (tid < s) red[tid] = fmaxf(red[tid], red[tid + s]);
    __syncthreads();
  }
  m = red[0];
  __syncthreads();
  float sum = 0.f;
  for (int i = tid; i < CV; i += 256) {
    float e = expf(p[i] - m);
    p[i] = e;
    sum += e;
  }
  red[tid] = sum;
  __syncthreads();
  for (int s = 128; s > 0; s >>= 1) {
    if (tid < s) red[tid] = red[tid] + red[tid + s];
    __syncthreads();
  }
  float inv = 1.f / red[0];
  for (int i = tid; i < CV; i += 256) p[i] *= inv;
}

extern "C" __global__ void init_bar(unsigned* bar) {
  bar[(size_t)blockIdx.x * 1024 + threadIdx.x] = 0u;   // 4 groups * 64 flags * 128B
}

extern "C" void kernel_launch(void* const* d_in, const int* in_sizes, int n_in,
                              void* d_out, int out_size, void* d_ws, size_t ws_size,
                              hipStream_t stream) {
  const float* x  = (const float*)d_in[0];
  const float* W  = (const float*)d_in[1];
  const float* U  = (const float*)d_in[2];
  const float* bb = (const float*)d_in[3];
  const float* Wd = (const float*)d_in[4];
  const float* bd = (const float*)d_in[5];
  float* out = (float*)d_out;

  char* ws = (char*)d_ws;
  unsigned* bar = (unsigned*)ws;                      // 32 KiB flag area
  float* hbuf  = (float*)(ws + 32768);
  float* xwbuf = (float*)(ws + 32768 + (size_t)2 * CB * CH * sizeof(float));

  // largest xW chunk that fits the workspace (Tc divides 512, multiple of 4)
  const int cands[7] = {512, 256, 128, 64, 32, 16, 8};
  int Tc = 4;
  for (int ci = 0; ci < 7; ++ci) {
    size_t need = 32768 + (size_t)2 * CB * CH * 4 + (size_t)cands[ci] * CB * CH * 4;
    if (need <= ws_size) { Tc = cands[ci]; break; }
  }

  hipLaunchKernelGGL(init_bar, dim3(8), dim3(1024), 0, stream, bar);

  void* args[8];
  args[0] = (void*)&x;     args[1] = (void*)&W;     args[2] = (void*)&U;   args[3] = (void*)&bb;
  args[4] = (void*)&hbuf;  args[5] = (void*)&xwbuf; args[6] = (void*)&bar; args[7] = (void*)&Tc;
  hipLaunchCooperativeKernel((void*)rnn_scan_kernel, dim3(256), dim3(512), args, 0, stream);

  // final h state lives in hbuf[0] (T=512 even)
  hipLaunchKernelGGL(logits_kernel, dim3(CV / 64), dim3(64), 0, stream, hbuf, Wd, bd, out);
  hipLaunchKernelGGL(softmax_kernel, dim3(CB), dim3(256), 0, stream, out);
}